// Round 1
// 120.506 us; speedup vs baseline: 1.0029x; 1.0029x over previous
//
#include <hip/hip_runtime.h>

// Problem constants (from reference)
#define Bn   256
#define Kn   500
#define Wn   272
#define HWn  (152 * 272)
#define TABLE 2048   // hash slots; ~400 nonzero ids2 per batch -> load ~0.2

// Structure: two kernels (R2/R3 established: fused atomic handoff regresses).
// This round: 512 threads/block (1 element/thread, 2 waves/SIMD instead of 1),
// flow gathers hoisted to kernel entry (address = index[b,x], independent of
// the hash probe -> latency overlaps table build instead of being exposed
// after the probe), TABLE 1024->2048 (shorter probe chains, LDS is free at
// 1 block/CU).

__global__ __launch_bounds__(512) void join_loss_kernel(
    const float* __restrict__ flow, const float* __restrict__ mask,
    const int* __restrict__ index, const int* __restrict__ ids,
    const int* __restrict__ index2, const int* __restrict__ ids2,
    float* __restrict__ partials /* [0,256)=loss, [256,512)=mask */) {
  const int b = blockIdx.x;
  const int tid = threadIdx.x;
  const bool act = tid < Kn;
  __shared__ int h_key[TABLE];
  __shared__ int h_val[TABLE];   // stores index2[b,j] directly

  // --- Issue ALL global loads upfront (independent -> overlapped latency) ---
  int   v2 = 0, i2v = 0, id = 0, hw = 0;
  float m = 0.f;
  if (act) {
    v2  = ids2[b * Kn + tid];
    i2v = index2[b * Kn + tid];
    id  = ids[b * Kn + tid];
    m   = mask[b * Kn + tid];
    hw  = index[b * Kn + tid];
  }
  // Hoisted flow gathers: address known now; result not needed until after
  // the probe, so ~900cy HBM latency hides under zero+build+barriers.
  float p0 = 0.f, p1 = 0.f;
  if (act) {
    p0 = flow[(size_t)(b * 2 + 0) * HWn + hw];
    p1 = flow[(size_t)(b * 2 + 1) * HWn + hw];
  }

  h_key[tid]        = 0;
  h_key[tid + 512]  = 0;
  h_key[tid + 1024] = 0;
  h_key[tid + 1536] = 0;
  __syncthreads();

  // --- Build hash: key = ids2 (nonzero, distinct per batch), val = index2 ---
  if (v2 != 0) {
    unsigned h = (((unsigned)v2 * 2654435761u) >> 21) & (TABLE - 1);
    while (true) {
      int old = atomicCAS(&h_key[h], 0, v2);
      if (old == 0) { h_val[h] = i2v; break; }
      if (old == v2) break;  // duplicates cannot occur per input construction
      h = (h + 1) & (TABLE - 1);
    }
  }
  __syncthreads();

  // --- Lookup + loss (ids >= 1 always; 0 is the empty sentinel) ---
  float lloss = 0.f, lmask = m;
  if (act) {
    unsigned h = (((unsigned)id * 2654435761u) >> 21) & (TABLE - 1);
    int i2 = -1;
    while (true) {
      int k = h_key[h];
      if (k == 0) break;
      if (k == id) { i2 = h_val[h]; break; }
      h = (h + 1) & (TABLE - 1);
    }
    if (i2 >= 0) {
      lloss = fabsf(p0 * m - (float)(i2 % Wn)) +
              fabsf(p1 * m - (float)i2 / 272.0f);
    }
  }

  // --- Block reduce (wave shuffle + LDS), plain stores to partials ---
  for (int off = 32; off; off >>= 1) {
    lloss += __shfl_down(lloss, off, 64);
    lmask += __shfl_down(lmask, off, 64);
  }
  __shared__ float s_l[8], s_m[8];
  const int wave = tid >> 6, lane = tid & 63;
  if (lane == 0) { s_l[wave] = lloss; s_m[wave] = lmask; }
  __syncthreads();
  if (tid == 0) {
    float L = 0.f, M = 0.f;
    #pragma unroll
    for (int i = 0; i < 8; ++i) { L += s_l[i]; M += s_m[i]; }
    partials[b]       = L;
    partials[256 + b] = M;
  }
}

// One wave: reduce 256 loss partials + 256 mask partials, write scalar.
__global__ __launch_bounds__(64) void finalize_kernel(
    const float* __restrict__ partials, float* __restrict__ out) {
  const int lane = threadIdx.x;
  float l = 0.f, m = 0.f;
  #pragma unroll
  for (int i = 0; i < 4; ++i) {
    l += partials[lane + 64 * i];
    m += partials[256 + lane + 64 * i];
  }
  for (int off = 32; off; off >>= 1) {
    l += __shfl_down(l, off, 64);
    m += __shfl_down(m, off, 64);
  }
  if (lane == 0) out[0] = l / (2.0f * m + 0.0001f);
}

extern "C" void kernel_launch(void* const* d_in, const int* in_sizes, int n_in,
                              void* d_out, int out_size, void* d_ws, size_t ws_size,
                              hipStream_t stream) {
  const float* flow   = (const float*)d_in[0];
  const float* mask   = (const float*)d_in[1];
  const int*   index  = (const int*)d_in[2];
  const int*   ids    = (const int*)d_in[3];
  const int*   index2 = (const int*)d_in[4];
  const int*   ids2   = (const int*)d_in[5];
  float* partials = (float*)d_ws;  // 512 floats: [0,256)=loss, [256,512)=mask
  join_loss_kernel<<<Bn, 512, 0, stream>>>(flow, mask, index, ids, index2, ids2, partials);
  finalize_kernel<<<1, 64, 0, stream>>>(partials, (float*)d_out);
}